// Round 6
// baseline (436.104 us; speedup 1.0000x reference)
//
#include <hip/hip_runtime.h>

#define F_LOC 25088
#define CDIM 512
#define VN 6
#define MN 160      // B*T
#define HWN 49
#define NCLS 8
#define KS12 8       // gemm12 k-split
#define KC12 3136    // F_LOC / KS12
#define KS3 16       // gemm3 k-split
#define KC3 1568     // F_LOC / KS3
#define ARS (VN * F_LOC)
#define LDSBUF 10624  // u16: A 160*40=6400 + B 32*66 fp32 = 4224

typedef __attribute__((ext_vector_type(8))) short short8;
typedef __attribute__((ext_vector_type(4))) float f32x4;
typedef unsigned short u16;

__device__ __forceinline__ u16 f2bf(float f) {
  union { float f; unsigned u; } x; x.f = f;
  unsigned r = x.u + 0x7fffu + ((x.u >> 16) & 1u);
  return (u16)(r >> 16);
}
__device__ __forceinline__ float sigf(float x) { return 1.0f / (1.0f + __expf(-x)); }

__global__ void k_initframe(float* __restrict__ frame, const float* __restrict__ bf) {
  int i = blockIdx.x * blockDim.x + threadIdx.x;
  if (i < MN * NCLS) frame[i] = bf[i & 7];
}

// ================= GEMM core: BOTH A and B LDS-staged, all global loads float4 =============
// Per step: LDS-write A(s) [160x32 fp32->bf16, pad 40] and B(s) [32x64 fp32, pad 66],
// one barrier, prefetch A(s+1)+B(s+1) into regs (full step of latency slack),
// B fragments via 8x ds_read_b32 (2-way banked = free), 10 MFMA. Dbuf LDS.
#define GSTEP(S, PH, DO_NEXT)                                                            \
  {                                                                                      \
    u16* bufA = lds + (PH)*LDSBUF;                                                       \
    float* bufB = (float*)(bufA + 6400);                                                 \
    _Pragma("unroll") for (int p = 0; p < 5; ++p) {                                      \
      int i = t + p * 256, row = i >> 3, q = i & 7;                                      \
      ushort4 o;                                                                         \
      o.x = f2bf(areg[p].x); o.y = f2bf(areg[p].y);                                      \
      o.z = f2bf(areg[p].z); o.w = f2bf(areg[p].w);                                      \
      *(ushort4*)(bufA + row * 40 + q * 4) = o;                                          \
    }                                                                                    \
    _Pragma("unroll") for (int p = 0; p < 2; ++p) {                                      \
      int i = t + p * 256;                                                               \
      *(float4*)(bufB + (i >> 4) * 66 + (i & 15) * 4) = breg[p];                         \
    }                                                                                    \
    __syncthreads();                                                                     \
    if (DO_NEXT) {                                                                       \
      _Pragma("unroll") for (int p = 0; p < 5; ++p) {                                    \
        int i = t + p * 256, row = i >> 3, q = i & 7;                                    \
        areg[p] = *(const float4*)(Ab + (size_t)row * a_rs + ((S) + 1) * 32 + q * 4);    \
      }                                                                                  \
      _Pragma("unroll") for (int p = 0; p < 2; ++p) {                                    \
        int i = t + p * 256;                                                             \
        breg[p] = *(const float4*)(Wb + (size_t)(((S) + 1) * 32 + (i >> 4)) * CDIM + (i & 15) * 4); \
      }                                                                                  \
    }                                                                                    \
    float bv[8];                                                                         \
    _Pragma("unroll") for (int j = 0; j < 8; ++j) bv[j] = bufB[(kg * 8 + j) * 66 + cl];  \
    short8 bfrag;                                                                        \
    _Pragma("unroll") for (int j = 0; j < 8; ++j) bfrag[j] = (short)f2bf(bv[j]);         \
    _Pragma("unroll") for (int mt = 0; mt < 10; ++mt) {                                  \
      short8 af = *(const short8*)(bufA + (l15 + 16 * mt) * 40 + kg * 8);                \
      acc[mt] = __builtin_amdgcn_mfma_f32_16x16x32_bf16(af, bfrag, acc[mt], 0, 0, 0);    \
    }                                                                                    \
  }

template <int NSTEP>
__device__ __forceinline__ void gemm_core(
    const float* __restrict__ Ab, int a_rs,   // A chunk base (fp32), row stride
    const float* __restrict__ Wb,             // W block base (+kbase*CDIM + cb*64)
    float* __restrict__ op,                   // out + lane's c column
    u16* __restrict__ lds, int t) {
  const int lane = t & 63;
  const int wv = t >> 6;
  const int l15 = lane & 15;
  const int kg = lane >> 4;
  const int cl = wv * 16 + l15;   // local c within block's 64 columns

  f32x4 acc[10];
#pragma unroll
  for (int i = 0; i < 10; ++i) acc[i] = (f32x4)(0.0f);

  float4 areg[5], breg[2];

  // prologue: A(0), B(0) — all coalesced float4
#pragma unroll
  for (int p = 0; p < 5; ++p) {
    int i = t + p * 256, row = i >> 3, q = i & 7;
    areg[p] = *(const float4*)(Ab + (size_t)row * a_rs + q * 4);
  }
#pragma unroll
  for (int p = 0; p < 2; ++p) {
    int i = t + p * 256;
    breg[p] = *(const float4*)(Wb + (size_t)(i >> 4) * CDIM + (i & 15) * 4);
  }

  for (int s = 0; s + 2 < NSTEP; s += 2) {
    GSTEP(s, 0, true);
    GSTEP(s + 1, 1, true);
  }
  if constexpr ((NSTEP & 1) == 0) {
    GSTEP(NSTEP - 2, 0, true);
    GSTEP(NSTEP - 1, 1, false);
  } else {
    GSTEP(NSTEP - 1, 0, false);
  }

#pragma unroll
  for (int mt = 0; mt < 10; ++mt)
#pragma unroll
    for (int i = 0; i < 4; ++i)
      op[(size_t)(mt * 16 + kg * 4 + i) * (VN * CDIM)] = acc[mt][i];  // D row = kg*4+i
}
#undef GSTEP

// ============ GEMM1+2: one dispatch, 768 blocks = one occupancy pass ============
// bid = sub*384 + cb*48 + (v*8+ks); bid%8 == ks for all 16 blocks (8cb x 2sub)
// sharing an A chunk -> same XCD, feats HBM-read once (2MB chunk fits 4MB L2).
__global__ __launch_bounds__(256, 3) void k_gemm12(
    const float* __restrict__ feats, const float* __restrict__ Wl,
    const float* __restrict__ Wgl, float* __restrict__ wpart, float* __restrict__ rpart) {
  __shared__ u16 lds[2 * LDSBUF];  // 42.5 KB
  int bid = blockIdx.x;
  int sub = bid / 384;
  int r = bid - sub * 384;
  int cb = r / 48;
  int g = r - cb * 48;
  int v = g >> 3, ks = g & 7;
  int t = threadIdx.x;
  int wv = t >> 6, l15 = t & 15;
  const float* Ab = feats + (size_t)v * F_LOC + (size_t)ks * KC12;
  const float* W = sub ? Wgl : Wl;
  long long wvs = sub ? (long long)2 * F_LOC * CDIM : (long long)F_LOC * CDIM;
  const float* Wb = W + (size_t)v * wvs + (size_t)ks * KC12 * CDIM + cb * 64;
  float* op = (sub ? rpart : wpart) + (size_t)ks * MN * (VN * CDIM) + (size_t)v * CDIM +
              cb * 64 + wv * 16 + l15;
  gemm_core<98>(Ab, ARS, Wb, op, lds, t);
}

// ============ GEMM3: A = agg (fp32, shared across v), W_global rows [F_LOC, 2F) ============
// 768 blocks; bid%8 == ks%8 invariant across cb,v -> agg chunk sharers on one XCD.
__global__ __launch_bounds__(256, 3) void k_gemm3(
    const float* __restrict__ agg, const float* __restrict__ Wgl, float* __restrict__ rpart) {
  __shared__ u16 lds[2 * LDSBUF];
  int b = blockIdx.x;
  int g = b % 96, cb = b / 96;
  int v = g / KS3, ks = g % KS3;
  int t = threadIdx.x;
  int wv = t >> 6, l15 = t & 15;
  const float* Ab = agg + (size_t)ks * KC3;
  const float* Wb = Wgl + (size_t)F_LOC * CDIM + (size_t)v * (2ll * F_LOC * CDIM) +
                    (size_t)ks * KC3 * CDIM + cb * 64;
  float* op = rpart + (size_t)(KS12 + ks) * MN * (VN * CDIM) + (size_t)v * CDIM +
              cb * 64 + wv * 16 + l15;
  gemm_core<49>(Ab, F_LOC, Wb, op, lds, t);
}

// ---------------- reduce partials + bias, w = sigmoid, w_norm = w/sum_c ----------------
__global__ void k_wnorm(const float* __restrict__ part, const float* __restrict__ bias,
                        float* __restrict__ w, float* __restrict__ wn, int nslot) {
  int v = blockIdx.x, m = blockIdx.y, t = threadIdx.x;
  const size_t slot_stride = (size_t)MN * VN * CDIM;
  size_t base = (size_t)m * (VN * CDIM) + v * CDIM;
  float s0 = bias[v * CDIM + t], s1 = bias[v * CDIM + t + 256];
  for (int j = 0; j < nslot; ++j) {
    s0 += part[j * slot_stride + base + t];
    s1 += part[j * slot_stride + base + t + 256];
  }
  s0 = sigf(s0); s1 = sigf(s1);
  w[base + t] = s0; w[base + t + 256] = s1;
  __shared__ float red[256];
  red[t] = s0 + s1;
  __syncthreads();
  for (int o = 128; o > 0; o >>= 1) { if (t < o) red[t] += red[t + o]; __syncthreads(); }
  float inv = 1.0f / red[0];
  wn[base + t] = s0 * inv; wn[base + t + 256] = s1 * inv;
}

__global__ void k_fwnorm(const float* __restrict__ part, const float* __restrict__ bias,
                         const float* __restrict__ w, float* __restrict__ fwn, int nslot) {
  int v = blockIdx.x, m = blockIdx.y, t = threadIdx.x;
  const size_t slot_stride = (size_t)MN * VN * CDIM;
  size_t base = (size_t)m * (VN * CDIM) + v * CDIM;
  float s0 = bias[v * CDIM + t], s1 = bias[v * CDIM + t + 256];
  for (int j = 0; j < nslot; ++j) {
    s0 += part[j * slot_stride + base + t];
    s1 += part[j * slot_stride + base + t + 256];
  }
  float f0 = w[base + t] * sigf(s0);
  float f1 = w[base + t + 256] * sigf(s1);
  __shared__ float red[256];
  red[t] = f0 + f1;
  __syncthreads();
  for (int o = 128; o > 0; o >>= 1) { if (t < o) red[t] += red[t + o]; __syncthreads(); }
  float inv = 1.0f / red[0];
  fwn[base + t] = f0 * inv; fwn[base + t + 256] = f1 * inv;
}

// ---------------- weighted view-aggregation, fused with W_final contribution ----------------
__global__ void k_aggregate(const float* __restrict__ feats, const float* __restrict__ wn,
                            float* __restrict__ aggf, const float* __restrict__ Wf,
                            float* __restrict__ frame, int wf_off) {
  int m = blockIdx.y;
  int cbase = blockIdx.x * 64;
  int t = threadIdx.x;
  float p[8] = {0, 0, 0, 0, 0, 0, 0, 0};
  for (int idx = t; idx < 64 * HWN; idx += 256) {
    int cl = idx / HWN;
    int hw = idx - cl * HWN;
    int c = cbase + cl;
    float val = 0.0f;
#pragma unroll
    for (int v = 0; v < VN; ++v)
      val += feats[(((size_t)m * VN + v) * CDIM + c) * HWN + hw] * wn[((size_t)m * VN + v) * CDIM + c];
    if (aggf) aggf[(size_t)m * F_LOC + c * HWN + hw] = val;
    const float* wr = Wf + ((size_t)wf_off + c * HWN + hw) * NCLS;
#pragma unroll
    for (int n = 0; n < NCLS; ++n) p[n] += val * wr[n];
  }
  __shared__ float red[256];
  for (int n = 0; n < NCLS; ++n) {
    red[t] = p[n];
    __syncthreads();
    for (int o = 128; o > 0; o >>= 1) { if (t < o) red[t] += red[t + o]; __syncthreads(); }
    if (t == 0) atomicAdd(&frame[m * NCLS + n], red[0]);
    __syncthreads();
  }
}

__global__ void k_out(const float* __restrict__ frame, const float* __restrict__ Wt,
                      const float* __restrict__ bt, float* __restrict__ out) {
  int t = threadIdx.x;  // 64
  int b = t >> 3, n = t & 7;
  float acc = bt[n];
  for (int k = 0; k < MN; ++k) acc += frame[b * MN + k] * Wt[k * NCLS + n];
  out[t] = acc;
}

extern "C" void kernel_launch(void* const* d_in, const int* in_sizes, int n_in,
                              void* d_out, int out_size, void* d_ws, size_t ws_size,
                              hipStream_t stream) {
  const float* feats    = (const float*)d_in[0];
  const float* W_local  = (const float*)d_in[1];
  const float* b_local  = (const float*)d_in[2];
  const float* W_global = (const float*)d_in[3];
  const float* b_global = (const float*)d_in[4];
  const float* W_final  = (const float*)d_in[5];
  const float* b_final  = (const float*)d_in[6];
  const float* W_time   = (const float*)d_in[7];
  const float* b_time   = (const float*)d_in[8];
  float* out = (float*)d_out;

  char* ws = (char*)d_ws;
  size_t off = 0;
  float* aggf   = (float*)(ws + off); off += (size_t)MN * F_LOC * 4;                        // 16 MB
  float* wpart  = (float*)(ws + off); off += (size_t)KS12 * MN * VN * CDIM * 4;             // 15.7 MB
  float* rpart  = (float*)(ws + off); off += (size_t)(KS12 + KS3) * MN * VN * CDIM * 4;     // 47.2 MB
  float* wbuf   = (float*)(ws + off); off += (size_t)MN * VN * CDIM * 4;
  float* wnorm  = (float*)(ws + off); off += (size_t)MN * VN * CDIM * 4;
  float* fwnorm = (float*)(ws + off); off += (size_t)MN * VN * CDIM * 4;
  float* frame  = (float*)(ws + off); off += 8192;

  k_initframe<<<(MN * NCLS + 255) / 256, 256, 0, stream>>>(frame, b_final);

  // w logits + r logits (feats part): 768 blocks = one residency pass
  k_gemm12<<<768, 256, 0, stream>>>(feats, W_local, W_global, wpart, rpart);
  k_wnorm<<<dim3(6, 160), 256, 0, stream>>>(wpart, b_local, wbuf, wnorm, KS12);
  // agg (+ W_final rows [F_LOC, 2F_LOC) -> frame), store agg fp32
  k_aggregate<<<dim3(8, 160), 256, 0, stream>>>(feats, wnorm, aggf, W_final, frame, F_LOC);
  // r logits, agg part -> rpart slots 8..23
  k_gemm3<<<768, 256, 0, stream>>>(aggf, W_global, rpart);
  k_fwnorm<<<dim3(6, 160), 256, 0, stream>>>(rpart, b_global, wbuf, fwnorm, KS12 + KS3);
  // refined contribution (W_final rows [0, F_LOC)) -> frame
  k_aggregate<<<dim3(8, 160), 256, 0, stream>>>(feats, fwnorm, nullptr, W_final, frame, 0);
  k_out<<<1, 64, 0, stream>>>(frame, W_time, b_time, out);
}

// Round 7
// 371.495 us; speedup vs baseline: 1.1739x; 1.1739x over previous
//
#include <hip/hip_runtime.h>

#define F_LOC 25088
#define CDIM 512
#define VN 6
#define MN 160      // B*T
#define HWN 49
#define NCLS 8
#define KS12 8       // gemm12 k-split
#define KC12 3136    // F_LOC / KS12, 49 steps of 64
#define KS3 16       // gemm3 k-split
#define KC3 1568     // F_LOC / KS3, 49 steps of 32
#define ARS (VN * F_LOC)

typedef __attribute__((ext_vector_type(8))) short short8;
typedef __attribute__((ext_vector_type(4))) float f32x4;
typedef unsigned short u16;

__device__ __forceinline__ u16 f2bf(float f) {
  union { float f; unsigned u; } x; x.f = f;
  unsigned r = x.u + 0x7fffu + ((x.u >> 16) & 1u);
  return (u16)(r >> 16);
}
__device__ __forceinline__ float sigf(float x) { return 1.0f / (1.0f + __expf(-x)); }

__global__ void k_initframe(float* __restrict__ frame, const float* __restrict__ bf) {
  int i = blockIdx.x * blockDim.x + threadIdx.x;
  if (i < MN * NCLS) frame[i] = bf[i & 7];
}

// ================= GEMM core: KH k-halves (step K = 32*KH), LDS-staged A =================
// Per step: LDS-write A(s) (fp32->bf16 from regs), ONE barrier, prefetch A(s+1),
// then per k-half: convert B, prefetch B(s+1,h), 10 MFMA. All prefetches drain at
// the barrier anyway (hipcc emits vmcnt(0) there) -- fatter steps amortize that.
// KH=2: rows padded to 72 u16 (144B -> ds_read 2-way banked, free).
// KH=1: rows padded to 40 u16 (80B, 2-way banked) -- identical to round-5 core.
template <int NSTEP, int KH>
__device__ __forceinline__ void gemm_core(
    const float* __restrict__ Ab, int a_rs,   // A chunk base (fp32), row stride
    const float* __restrict__ Wp,             // W + lane's c column
    float* __restrict__ op,                   // out + lane's c column
    u16* __restrict__ lds, int t) {
  const int lane = t & 63;
  const int l15 = lane & 15;
  const int kg = lane >> 4;
  constexpr int RP = (KH == 2) ? 72 : 40;    // row pad (u16)
  constexpr int NLD = 5 * KH;                // float4 per thread per step
  constexpr int LB = 160 * RP;               // u16 per LDS buffer

  f32x4 acc[10];
#pragma unroll
  for (int i = 0; i < 10; ++i) acc[i] = (f32x4)(0.0f);

  float4 areg[NLD];
  float bR[KH][8];

  // prologue: A(0) first, then B(0) (FIFO: A-wait never drains B)
#pragma unroll
  for (int p = 0; p < NLD; ++p) {
    int i = t + p * 256;
    int row = (KH == 2) ? (i >> 4) : (i >> 3);
    int q = (KH == 2) ? (i & 15) : (i & 7);
    areg[p] = *(const float4*)(Ab + (size_t)row * a_rs + q * 4);
  }
#pragma unroll
  for (int h = 0; h < KH; ++h)
#pragma unroll
    for (int j = 0; j < 8; ++j) bR[h][j] = Wp[(size_t)(h * 32 + kg * 8 + j) * CDIM];

  for (int s = 0; s < NSTEP; ++s) {
    u16* buf = lds + (s & 1) * LB;
#pragma unroll
    for (int p = 0; p < NLD; ++p) {
      int i = t + p * 256;
      int row = (KH == 2) ? (i >> 4) : (i >> 3);
      int q = (KH == 2) ? (i & 15) : (i & 7);
      ushort4 o;
      o.x = f2bf(areg[p].x); o.y = f2bf(areg[p].y);
      o.z = f2bf(areg[p].z); o.w = f2bf(areg[p].w);
      *(ushort4*)(buf + row * RP + q * 4) = o;
    }
    __syncthreads();
    const bool more = (s + 1) < NSTEP;
    if (more) {
#pragma unroll
      for (int p = 0; p < NLD; ++p) {
        int i = t + p * 256;
        int row = (KH == 2) ? (i >> 4) : (i >> 3);
        int q = (KH == 2) ? (i & 15) : (i & 7);
        areg[p] = *(const float4*)(Ab + (size_t)row * a_rs + (s + 1) * (32 * KH) + q * 4);
      }
    }
#pragma unroll
    for (int h = 0; h < KH; ++h) {
      short8 bfrag;
#pragma unroll
      for (int j = 0; j < 8; ++j) bfrag[j] = (short)f2bf(bR[h][j]);
      if (more) {
#pragma unroll
        for (int j = 0; j < 8; ++j)
          bR[h][j] = Wp[(size_t)((s + 1) * (32 * KH) + h * 32 + kg * 8 + j) * CDIM];
      }
#pragma unroll
      for (int mt = 0; mt < 10; ++mt) {
        short8 af = *(const short8*)(buf + (l15 + 16 * mt) * RP + h * 32 + kg * 8);
        acc[mt] = __builtin_amdgcn_mfma_f32_16x16x32_bf16(af, bfrag, acc[mt], 0, 0, 0);
      }
    }
  }

#pragma unroll
  for (int mt = 0; mt < 10; ++mt)
#pragma unroll
    for (int i = 0; i < 4; ++i)
      op[(size_t)(mt * 16 + kg * 4 + i) * (VN * CDIM)] = acc[mt][i];  // D row = kg*4+i
}

// ============ GEMM1+2: one dispatch, 768 blocks = one occupancy pass, BK=64 ============
// bid = sub*384 + cb*48 + (v*8+ks); bid%8 == ks for all 16 blocks (8cb x 2sub)
// sharing an A chunk -> same XCD, feats HBM-read once (2MB chunk fits 4MB L2).
__global__ __launch_bounds__(256, 3) void k_gemm12(
    const float* __restrict__ feats, const float* __restrict__ Wl,
    const float* __restrict__ Wgl, float* __restrict__ wpart, float* __restrict__ rpart) {
  __shared__ u16 lds[2 * 160 * 72];  // 46.1 KB
  int bid = blockIdx.x;
  int sub = bid / 384;
  int r = bid - sub * 384;
  int cb = r / 48;
  int g = r - cb * 48;
  int v = g >> 3, ks = g & 7;
  int t = threadIdx.x;
  int wv = t >> 6, l15 = t & 15;
  int c = cb * 64 + wv * 16 + l15;
  const float* Ab = feats + (size_t)v * F_LOC + (size_t)ks * KC12;
  const float* W = sub ? Wgl : Wl;
  long long wvs = sub ? (long long)2 * F_LOC * CDIM : (long long)F_LOC * CDIM;
  const float* Wp = W + (size_t)v * wvs + (size_t)ks * KC12 * CDIM + c;
  float* op = (sub ? rpart : wpart) + (size_t)ks * MN * (VN * CDIM) + (size_t)v * CDIM + c;
  gemm_core<49, 2>(Ab, ARS, Wp, op, lds, t);
}

// ============ GEMM3 (CONTROL, unchanged): A = agg fp32, W_global rows [F_LOC, 2F) ============
// 768 blocks; bid%8 == ks%8 invariant across cb,v -> agg chunk sharers on one XCD.
__global__ __launch_bounds__(256, 3) void k_gemm3(
    const float* __restrict__ agg, const float* __restrict__ Wgl, float* __restrict__ rpart) {
  __shared__ u16 lds[2 * 160 * 40];  // 25.6 KB
  int b = blockIdx.x;
  int g = b % 96, cb = b / 96;
  int v = g / KS3, ks = g % KS3;
  int t = threadIdx.x;
  int wv = t >> 6, l15 = t & 15;
  int c = cb * 64 + wv * 16 + l15;
  const float* Ab = agg + (size_t)ks * KC3;
  const float* Wp = Wgl + (size_t)F_LOC * CDIM + (size_t)v * (2ll * F_LOC * CDIM) +
                    (size_t)ks * KC3 * CDIM + c;
  float* op = rpart + (size_t)(KS12 + ks) * MN * (VN * CDIM) + (size_t)v * CDIM + c;
  gemm_core<49, 1>(Ab, F_LOC, Wp, op, lds, t);
}

// ---------------- reduce partials + bias, w = sigmoid, w_norm = w/sum_c ----------------
__global__ void k_wnorm(const float* __restrict__ part, const float* __restrict__ bias,
                        float* __restrict__ w, float* __restrict__ wn, int nslot) {
  int v = blockIdx.x, m = blockIdx.y, t = threadIdx.x;
  const size_t slot_stride = (size_t)MN * VN * CDIM;
  size_t base = (size_t)m * (VN * CDIM) + v * CDIM;
  float s0 = bias[v * CDIM + t], s1 = bias[v * CDIM + t + 256];
  for (int j = 0; j < nslot; ++j) {
    s0 += part[j * slot_stride + base + t];
    s1 += part[j * slot_stride + base + t + 256];
  }
  s0 = sigf(s0); s1 = sigf(s1);
  w[base + t] = s0; w[base + t + 256] = s1;
  __shared__ float red[256];
  red[t] = s0 + s1;
  __syncthreads();
  for (int o = 128; o > 0; o >>= 1) { if (t < o) red[t] += red[t + o]; __syncthreads(); }
  float inv = 1.0f / red[0];
  wn[base + t] = s0 * inv; wn[base + t + 256] = s1 * inv;
}

__global__ void k_fwnorm(const float* __restrict__ part, const float* __restrict__ bias,
                         const float* __restrict__ w, float* __restrict__ fwn, int nslot) {
  int v = blockIdx.x, m = blockIdx.y, t = threadIdx.x;
  const size_t slot_stride = (size_t)MN * VN * CDIM;
  size_t base = (size_t)m * (VN * CDIM) + v * CDIM;
  float s0 = bias[v * CDIM + t], s1 = bias[v * CDIM + t + 256];
  for (int j = 0; j < nslot; ++j) {
    s0 += part[j * slot_stride + base + t];
    s1 += part[j * slot_stride + base + t + 256];
  }
  float f0 = w[base + t] * sigf(s0);
  float f1 = w[base + t + 256] * sigf(s1);
  __shared__ float red[256];
  red[t] = f0 + f1;
  __syncthreads();
  for (int o = 128; o > 0; o >>= 1) { if (t < o) red[t] += red[t + o]; __syncthreads(); }
  float inv = 1.0f / red[0];
  fwn[base + t] = f0 * inv; fwn[base + t + 256] = f1 * inv;
}

// ---------------- weighted view-aggregation, fused with W_final contribution ----------------
__global__ void k_aggregate(const float* __restrict__ feats, const float* __restrict__ wn,
                            float* __restrict__ aggf, const float* __restrict__ Wf,
                            float* __restrict__ frame, int wf_off) {
  int m = blockIdx.y;
  int cbase = blockIdx.x * 64;
  int t = threadIdx.x;
  float p[8] = {0, 0, 0, 0, 0, 0, 0, 0};
  for (int idx = t; idx < 64 * HWN; idx += 256) {
    int cl = idx / HWN;
    int hw = idx - cl * HWN;
    int c = cbase + cl;
    float val = 0.0f;
#pragma unroll
    for (int v = 0; v < VN; ++v)
      val += feats[(((size_t)m * VN + v) * CDIM + c) * HWN + hw] * wn[((size_t)m * VN + v) * CDIM + c];
    if (aggf) aggf[(size_t)m * F_LOC + c * HWN + hw] = val;
    const float* wr = Wf + ((size_t)wf_off + c * HWN + hw) * NCLS;
#pragma unroll
    for (int n = 0; n < NCLS; ++n) p[n] += val * wr[n];
  }
  __shared__ float red[256];
  for (int n = 0; n < NCLS; ++n) {
    red[t] = p[n];
    __syncthreads();
    for (int o = 128; o > 0; o >>= 1) { if (t < o) red[t] += red[t + o]; __syncthreads(); }
    if (t == 0) atomicAdd(&frame[m * NCLS + n], red[0]);
    __syncthreads();
  }
}

__global__ void k_out(const float* __restrict__ frame, const float* __restrict__ Wt,
                      const float* __restrict__ bt, float* __restrict__ out) {
  int t = threadIdx.x;  // 64
  int b = t >> 3, n = t & 7;
  float acc = bt[n];
  for (int k = 0; k < MN; ++k) acc += frame[b * MN + k] * Wt[k * NCLS + n];
  out[t] = acc;
}

extern "C" void kernel_launch(void* const* d_in, const int* in_sizes, int n_in,
                              void* d_out, int out_size, void* d_ws, size_t ws_size,
                              hipStream_t stream) {
  const float* feats    = (const float*)d_in[0];
  const float* W_local  = (const float*)d_in[1];
  const float* b_local  = (const float*)d_in[2];
  const float* W_global = (const float*)d_in[3];
  const float* b_global = (const float*)d_in[4];
  const float* W_final  = (const float*)d_in[5];
  const float* b_final  = (const float*)d_in[6];
  const float* W_time   = (const float*)d_in[7];
  const float* b_time   = (const float*)d_in[8];
  float* out = (float*)d_out;

  char* ws = (char*)d_ws;
  size_t off = 0;
  float* aggf   = (float*)(ws + off); off += (size_t)MN * F_LOC * 4;                        // 16 MB
  float* wpart  = (float*)(ws + off); off += (size_t)KS12 * MN * VN * CDIM * 4;             // 15.7 MB
  float* rpart  = (float*)(ws + off); off += (size_t)(KS12 + KS3) * MN * VN * CDIM * 4;     // 47.2 MB
  float* wbuf   = (float*)(ws + off); off += (size_t)MN * VN * CDIM * 4;
  float* wnorm  = (float*)(ws + off); off += (size_t)MN * VN * CDIM * 4;
  float* fwnorm = (float*)(ws + off); off += (size_t)MN * VN * CDIM * 4;
  float* frame  = (float*)(ws + off); off += 8192;

  k_initframe<<<(MN * NCLS + 255) / 256, 256, 0, stream>>>(frame, b_final);

  // w logits + r logits (feats part): 768 blocks = one residency pass, BK=64
  k_gemm12<<<768, 256, 0, stream>>>(feats, W_local, W_global, wpart, rpart);
  k_wnorm<<<dim3(6, 160), 256, 0, stream>>>(wpart, b_local, wbuf, wnorm, KS12);
  // agg (+ W_final rows [F_LOC, 2F_LOC) -> frame), store agg fp32
  k_aggregate<<<dim3(8, 160), 256, 0, stream>>>(feats, wnorm, aggf, W_final, frame, F_LOC);
  // r logits, agg part -> rpart slots 8..23
  k_gemm3<<<768, 256, 0, stream>>>(aggf, W_global, rpart);
  k_fwnorm<<<dim3(6, 160), 256, 0, stream>>>(rpart, b_global, wbuf, fwnorm, KS12 + KS3);
  // refined contribution (W_final rows [0, F_LOC)) -> frame
  k_aggregate<<<dim3(8, 160), 256, 0, stream>>>(feats, fwnorm, nullptr, W_final, frame, 0);
  k_out<<<1, 64, 0, stream>>>(frame, W_time, b_time, out);
}

// Round 8
// 363.021 us; speedup vs baseline: 1.2013x; 1.0233x over previous
//
#include <hip/hip_runtime.h>

#define F_LOC 25088
#define CDIM 512
#define VN 6
#define MN 160      // B*T
#define HWN 49
#define NCLS 8
#define KS12 8       // gemm12 k-split
#define KC12 3136    // F_LOC / KS12, 49 steps of 64
#define KS3 14       // gemm3 k-split
#define KC3 1792     // F_LOC / KS3, 28 steps of 64
#define NSLOT (KS12 + KS3)
#define ARS (VN * F_LOC)

typedef __attribute__((ext_vector_type(8))) short short8;
typedef __attribute__((ext_vector_type(4))) float f32x4;
typedef unsigned short u16;

__device__ __forceinline__ u16 f2bf(float f) {
  union { float f; unsigned u; } x; x.f = f;
  unsigned r = x.u + 0x7fffu + ((x.u >> 16) & 1u);
  return (u16)(r >> 16);
}
__device__ __forceinline__ float sigf(float x) { return 1.0f / (1.0f + __expf(-x)); }

// ================= GEMM core: KH k-halves (step K = 32*KH), LDS-staged A =================
// Per step: LDS-write A(s) (fp32->bf16 from regs), ONE barrier, prefetch A(s+1),
// then per k-half: convert B, prefetch B(s+1,h), 10 MFMA. Fat steps amortize the
// vmcnt(0)-at-barrier drain (validated: BK 32->64 on gemm12 saved ~27us, R7).
// KH=2: rows padded to 72 u16 (144B -> ds_read 2-way banked, free).
template <int NSTEP, int KH>
__device__ __forceinline__ void gemm_core(
    const float* __restrict__ Ab, int a_rs,   // A chunk base (fp32), row stride
    const float* __restrict__ Wp,             // W + lane's c column
    float* __restrict__ op,                   // out + lane's c column
    u16* __restrict__ lds, int t) {
  const int lane = t & 63;
  const int l15 = lane & 15;
  const int kg = lane >> 4;
  constexpr int RP = (KH == 2) ? 72 : 40;    // row pad (u16)
  constexpr int NLD = 5 * KH;                // float4 per thread per step
  constexpr int LB = 160 * RP;               // u16 per LDS buffer

  f32x4 acc[10];
#pragma unroll
  for (int i = 0; i < 10; ++i) acc[i] = (f32x4)(0.0f);

  float4 areg[NLD];
  float bR[KH][8];

  // prologue: A(0) first, then B(0) (FIFO: A-wait never drains B)
#pragma unroll
  for (int p = 0; p < NLD; ++p) {
    int i = t + p * 256;
    int row = (KH == 2) ? (i >> 4) : (i >> 3);
    int q = (KH == 2) ? (i & 15) : (i & 7);
    areg[p] = *(const float4*)(Ab + (size_t)row * a_rs + q * 4);
  }
#pragma unroll
  for (int h = 0; h < KH; ++h)
#pragma unroll
    for (int j = 0; j < 8; ++j) bR[h][j] = Wp[(size_t)(h * 32 + kg * 8 + j) * CDIM];

  for (int s = 0; s < NSTEP; ++s) {
    u16* buf = lds + (s & 1) * LB;
#pragma unroll
    for (int p = 0; p < NLD; ++p) {
      int i = t + p * 256;
      int row = (KH == 2) ? (i >> 4) : (i >> 3);
      int q = (KH == 2) ? (i & 15) : (i & 7);
      ushort4 o;
      o.x = f2bf(areg[p].x); o.y = f2bf(areg[p].y);
      o.z = f2bf(areg[p].z); o.w = f2bf(areg[p].w);
      *(ushort4*)(buf + row * RP + q * 4) = o;
    }
    __syncthreads();
    const bool more = (s + 1) < NSTEP;
    if (more) {
#pragma unroll
      for (int p = 0; p < NLD; ++p) {
        int i = t + p * 256;
        int row = (KH == 2) ? (i >> 4) : (i >> 3);
        int q = (KH == 2) ? (i & 15) : (i & 7);
        areg[p] = *(const float4*)(Ab + (size_t)row * a_rs + (s + 1) * (32 * KH) + q * 4);
      }
    }
#pragma unroll
    for (int h = 0; h < KH; ++h) {
      short8 bfrag;
#pragma unroll
      for (int j = 0; j < 8; ++j) bfrag[j] = (short)f2bf(bR[h][j]);
      if (more) {
#pragma unroll
        for (int j = 0; j < 8; ++j)
          bR[h][j] = Wp[(size_t)((s + 1) * (32 * KH) + h * 32 + kg * 8 + j) * CDIM];
      }
#pragma unroll
      for (int mt = 0; mt < 10; ++mt) {
        short8 af = *(const short8*)(buf + (l15 + 16 * mt) * RP + h * 32 + kg * 8);
        acc[mt] = __builtin_amdgcn_mfma_f32_16x16x32_bf16(af, bfrag, acc[mt], 0, 0, 0);
      }
    }
  }

#pragma unroll
  for (int mt = 0; mt < 10; ++mt)
#pragma unroll
    for (int i = 0; i < 4; ++i)
      op[(size_t)(mt * 16 + kg * 4 + i) * (VN * CDIM)] = acc[mt][i];  // D row = kg*4+i
}

// ============ GEMM1+2: one dispatch, 768 blocks = one occupancy pass, BK=64 ============
// bid = sub*384 + cb*48 + (v*8+ks); bid%8 == ks for all 16 blocks (8cb x 2sub)
// sharing an A chunk -> same XCD, feats HBM-read once (2MB chunk fits 4MB L2).
__global__ __launch_bounds__(256, 3) void k_gemm12(
    const float* __restrict__ feats, const float* __restrict__ Wl,
    const float* __restrict__ Wgl, float* __restrict__ wpart, float* __restrict__ rpart) {
  __shared__ u16 lds[2 * 160 * 72];  // 46.1 KB
  int bid = blockIdx.x;
  int sub = bid / 384;
  int r = bid - sub * 384;
  int cb = r / 48;
  int g = r - cb * 48;
  int v = g >> 3, ks = g & 7;
  int t = threadIdx.x;
  int wv = t >> 6, l15 = t & 15;
  int c = cb * 64 + wv * 16 + l15;
  const float* Ab = feats + (size_t)v * F_LOC + (size_t)ks * KC12;
  const float* W = sub ? Wgl : Wl;
  long long wvs = sub ? (long long)2 * F_LOC * CDIM : (long long)F_LOC * CDIM;
  const float* Wp = W + (size_t)v * wvs + (size_t)ks * KC12 * CDIM + c;
  float* op = (sub ? rpart : wpart) + (size_t)ks * MN * (VN * CDIM) + (size_t)v * CDIM + c;
  gemm_core<49, 2>(Ab, ARS, Wp, op, lds, t);
}

// ============ GEMM3: BK=64 now too. A = agg fp32, W_global rows [F_LOC, 2F) ============
// bid = cb*96 + v*16 + ks, ks<14 (ks 14,15 exit): bid%8 == ks%8 invariant across
// cb AND v (v stride 16) -> all 48 blocks sharing an agg chunk keep XCD affinity.
__global__ __launch_bounds__(256, 3) void k_gemm3(
    const float* __restrict__ agg, const float* __restrict__ Wgl, float* __restrict__ rpart) {
  __shared__ u16 lds[2 * 160 * 72];
  int b = blockIdx.x;
  int g = b % 96, cb = b / 96;
  int v = g >> 4, ks = g & 15;
  if (ks >= KS3) return;
  int t = threadIdx.x;
  int wv = t >> 6, l15 = t & 15;
  int c = cb * 64 + wv * 16 + l15;
  const float* Ab = agg + (size_t)ks * KC3;
  const float* Wp = Wgl + (size_t)F_LOC * CDIM + (size_t)v * (2ll * F_LOC * CDIM) +
                    (size_t)ks * KC3 * CDIM + c;
  float* op = rpart + (size_t)(KS12 + ks) * MN * (VN * CDIM) + (size_t)v * CDIM + c;
  gemm_core<28, 2>(Ab, F_LOC, Wp, op, lds, t);
}

// ------- reduce partials + bias, w = sigmoid, w_norm = w/sum_c; v==0 inits frame -------
__global__ void k_wnorm(const float* __restrict__ part, const float* __restrict__ bias,
                        float* __restrict__ w, float* __restrict__ wn,
                        float* __restrict__ frame, const float* __restrict__ bf, int nslot) {
  int v = blockIdx.x, m = blockIdx.y, t = threadIdx.x;
  if (v == 0 && t < NCLS) frame[m * NCLS + t] = bf[t];
  const size_t slot_stride = (size_t)MN * VN * CDIM;
  size_t base = (size_t)m * (VN * CDIM) + v * CDIM;
  float s0 = bias[v * CDIM + t], s1 = bias[v * CDIM + t + 256];
  for (int j = 0; j < nslot; ++j) {
    s0 += part[j * slot_stride + base + t];
    s1 += part[j * slot_stride + base + t + 256];
  }
  s0 = sigf(s0); s1 = sigf(s1);
  w[base + t] = s0; w[base + t + 256] = s1;
  __shared__ float red[256];
  red[t] = s0 + s1;
  __syncthreads();
  for (int o = 128; o > 0; o >>= 1) { if (t < o) red[t] += red[t + o]; __syncthreads(); }
  float inv = 1.0f / red[0];
  wn[base + t] = s0 * inv; wn[base + t + 256] = s1 * inv;
}

__global__ void k_fwnorm(const float* __restrict__ part, const float* __restrict__ bias,
                         const float* __restrict__ w, float* __restrict__ fwn, int nslot) {
  int v = blockIdx.x, m = blockIdx.y, t = threadIdx.x;
  const size_t slot_stride = (size_t)MN * VN * CDIM;
  size_t base = (size_t)m * (VN * CDIM) + v * CDIM;
  float s0 = bias[v * CDIM + t], s1 = bias[v * CDIM + t + 256];
  for (int j = 0; j < nslot; ++j) {
    s0 += part[j * slot_stride + base + t];
    s1 += part[j * slot_stride + base + t + 256];
  }
  float f0 = w[base + t] * sigf(s0);
  float f1 = w[base + t + 256] * sigf(s1);
  __shared__ float red[256];
  red[t] = f0 + f1;
  __syncthreads();
  for (int o = 128; o > 0; o >>= 1) { if (t < o) red[t] += red[t + o]; __syncthreads(); }
  float inv = 1.0f / red[0];
  fwn[base + t] = f0 * inv; fwn[base + t + 256] = f1 * inv;
}

// ---------------- weighted view-aggregation, fused with W_final contribution ----------------
__global__ void k_aggregate(const float* __restrict__ feats, const float* __restrict__ wn,
                            float* __restrict__ aggf, const float* __restrict__ Wf,
                            float* __restrict__ frame, int wf_off) {
  int m = blockIdx.y;
  int cbase = blockIdx.x * 64;
  int t = threadIdx.x;
  float p[8] = {0, 0, 0, 0, 0, 0, 0, 0};
  for (int idx = t; idx < 64 * HWN; idx += 256) {
    int cl = idx / HWN;
    int hw = idx - cl * HWN;
    int c = cbase + cl;
    float val = 0.0f;
#pragma unroll
    for (int v = 0; v < VN; ++v)
      val += feats[(((size_t)m * VN + v) * CDIM + c) * HWN + hw] * wn[((size_t)m * VN + v) * CDIM + c];
    if (aggf) aggf[(size_t)m * F_LOC + c * HWN + hw] = val;
    const float* wr = Wf + ((size_t)wf_off + c * HWN + hw) * NCLS;
#pragma unroll
    for (int n = 0; n < NCLS; ++n) p[n] += val * wr[n];
  }
  __shared__ float red[256];
  for (int n = 0; n < NCLS; ++n) {
    red[t] = p[n];
    __syncthreads();
    for (int o = 128; o > 0; o >>= 1) { if (t < o) red[t] += red[t + o]; __syncthreads(); }
    if (t == 0) atomicAdd(&frame[m * NCLS + n], red[0]);
    __syncthreads();
  }
}

__global__ void k_out(const float* __restrict__ frame, const float* __restrict__ Wt,
                      const float* __restrict__ bt, float* __restrict__ out) {
  int t = threadIdx.x;  // 64
  int b = t >> 3, n = t & 7;
  float acc = bt[n];
  for (int k = 0; k < MN; ++k) acc += frame[b * MN + k] * Wt[k * NCLS + n];
  out[t] = acc;
}

extern "C" void kernel_launch(void* const* d_in, const int* in_sizes, int n_in,
                              void* d_out, int out_size, void* d_ws, size_t ws_size,
                              hipStream_t stream) {
  const float* feats    = (const float*)d_in[0];
  const float* W_local  = (const float*)d_in[1];
  const float* b_local  = (const float*)d_in[2];
  const float* W_global = (const float*)d_in[3];
  const float* b_global = (const float*)d_in[4];
  const float* W_final  = (const float*)d_in[5];
  const float* b_final  = (const float*)d_in[6];
  const float* W_time   = (const float*)d_in[7];
  const float* b_time   = (const float*)d_in[8];
  float* out = (float*)d_out;

  char* ws = (char*)d_ws;
  size_t off = 0;
  float* aggf   = (float*)(ws + off); off += (size_t)MN * F_LOC * 4;                    // 16 MB
  float* wpart  = (float*)(ws + off); off += (size_t)KS12 * MN * VN * CDIM * 4;         // 15.7 MB
  float* rpart  = (float*)(ws + off); off += (size_t)NSLOT * MN * VN * CDIM * 4;        // 43.3 MB
  float* wbuf   = (float*)(ws + off); off += (size_t)MN * VN * CDIM * 4;
  float* wnorm  = (float*)(ws + off); off += (size_t)MN * VN * CDIM * 4;
  float* fwnorm = (float*)(ws + off); off += (size_t)MN * VN * CDIM * 4;
  float* frame  = (float*)(ws + off); off += 8192;

  // w logits + r logits (feats part): 768 blocks = one residency pass, BK=64
  k_gemm12<<<768, 256, 0, stream>>>(feats, W_local, W_global, wpart, rpart);
  // reduce + sigmoid + normalize; also inits frame with b_final (v==0 blocks)
  k_wnorm<<<dim3(6, 160), 256, 0, stream>>>(wpart, b_local, wbuf, wnorm, frame, b_final, KS12);
  // agg (+ W_final rows [F_LOC, 2F_LOC) -> frame), store agg fp32
  k_aggregate<<<dim3(8, 160), 256, 0, stream>>>(feats, wnorm, aggf, W_final, frame, F_LOC);
  // r logits, agg part -> rpart slots 8..21, BK=64
  k_gemm3<<<768, 256, 0, stream>>>(aggf, W_global, rpart);
  k_fwnorm<<<dim3(6, 160), 256, 0, stream>>>(rpart, b_global, wbuf, fwnorm, NSLOT);
  // refined contribution (W_final rows [0, F_LOC)) -> frame
  k_aggregate<<<dim3(8, 160), 256, 0, stream>>>(feats, fwnorm, nullptr, W_final, frame, 0);
  k_out<<<1, 64, 0, stream>>>(frame, W_time, b_time, out);
}